// Round 10
// baseline (186.617 us; speedup 1.0000x reference)
//
#include <hip/hip_runtime.h>
#include <hip/hip_bf16.h>
#include <cstdint>
#include <cstddef>

typedef __bf16 bf16;
typedef __bf16 bf16x4 __attribute__((ext_vector_type(4)));
typedef __bf16 bf16x8 __attribute__((ext_vector_type(8)));
typedef float f32x4 __attribute__((ext_vector_type(4)));
typedef float f32x16 __attribute__((ext_vector_type(16)));

#define LOG2E 1.4426950408889634f
#define QSCALE (0.03125f * LOG2E)   // C^-0.5 * log2(e), folded into Q

#define GLD16(gp, lp)                                                              \
  __builtin_amdgcn_global_load_lds((__attribute__((address_space(1))) void*)(gp),  \
                                   (__attribute__((address_space(3))) void*)(lp),  \
                                   16, 0, 0)

// ---------------- fused prep: x->bf16 + W_qkv^T + W_out^T (one launch) ----------------
__global__ void k_prep(const float* __restrict__ x, const float* __restrict__ Wqkv,
                       const float* __restrict__ Wout, bf16* __restrict__ xb,
                       bf16* __restrict__ wqT, bf16* __restrict__ woT) {
  const int blk = blockIdx.x, tid = threadIdx.x;
  if (blk < 2048) {  // cvt x: 2048 blocks x 256 thr x 8 elems
    int i = (blk * 256 + tid) * 8;
    const float4* p = (const float4*)(x + i);
    float4 a = p[0], b = p[1];
    bf16x8 o;
    o[0] = (bf16)a.x; o[1] = (bf16)a.y; o[2] = (bf16)a.z; o[3] = (bf16)a.w;
    o[4] = (bf16)b.x; o[5] = (bf16)b.y; o[6] = (bf16)b.z; o[7] = (bf16)b.w;
    *(bf16x8*)(xb + i) = o;
    return;
  }
  // transposes: [R][C] fp32 -> [C][R] bf16, 32x32 tiles, 256 thr as (32,8)
  const float* in;
  bf16* out;
  int R = 1024, C, bx, by;
  if (blk < 2048 + 3072) {
    in = Wqkv; out = wqT; C = 3072;
    bx = (blk - 2048) % 96; by = (blk - 2048) / 96;
  } else {
    in = Wout; out = woT; C = 1024;
    bx = (blk - 5120) % 32; by = (blk - 5120) / 32;
  }
  __shared__ float t[32][33];
  const int tx = tid & 31, ty = tid >> 5;
  int c0 = bx * 32, r0 = by * 32;
#pragma unroll
  for (int i = 0; i < 4; i++)
    t[ty + i * 8][tx] = in[(size_t)(r0 + ty + i * 8) * C + c0 + tx];
  __syncthreads();
#pragma unroll
  for (int i = 0; i < 4; i++)
    out[(size_t)(c0 + ty + i * 8) * R + r0 + tx] = (bf16)t[tx][ty + i * 8];
}

// ---------------- QKV GEMM: C = A[4096,1024] @ Bt[3072,1024]^T ----------------
// (round-4 measured version.)
__global__ __launch_bounds__(256, 3) void k_gemm_qkv(
    const bf16* __restrict__ A, const bf16* __restrict__ Bt,
    const float* __restrict__ bias,
    bf16* __restrict__ qb, bf16* __restrict__ kb, bf16* __restrict__ vb) {
  __shared__ __align__(16) bf16 As[128 * 32];
  __shared__ __align__(16) bf16 Bs[128 * 32];
  const int tid = threadIdx.x;
  const int lane = tid & 63, w = tid >> 6;
  const int quad = lane >> 4, l16 = lane & 15;
  const int wm = (w >> 1) * 64, wn = (w & 1) * 64;
  const int bm = blockIdx.y * 128, bn = blockIdx.x * 128;
  f32x4 acc[4][4] = {};

  for (int kt = 0; kt < 1024; kt += 32) {
    __syncthreads();
#pragma unroll
    for (int p = 0; p < 2; p++) {
      int idx = p * 256 + tid;
      int row = idx >> 2, bq = idx & 3;
      int gb = (bq - ((row >> 1) & 3)) & 3;
      GLD16(A + (size_t)(bm + row) * 1024 + kt + gb * 8, As + idx * 8);
      GLD16(Bt + (size_t)(bn + row) * 1024 + kt + gb * 8, Bs + idx * 8);
    }
    __syncthreads();

    bf16x8 af[4], bfr[4];
#pragma unroll
    for (int mi = 0; mi < 4; mi++) {
      int row = wm + mi * 16 + l16;
      int bq = (quad + ((row >> 1) & 3)) & 3;
      af[mi] = *(const bf16x8*)(As + row * 32 + bq * 8);
    }
#pragma unroll
    for (int ni = 0; ni < 4; ni++) {
      int row = wn + ni * 16 + l16;
      int bq = (quad + ((row >> 1) & 3)) & 3;
      bfr[ni] = *(const bf16x8*)(Bs + row * 32 + bq * 8);
    }
#pragma unroll
    for (int mi = 0; mi < 4; mi++)
#pragma unroll
      for (int ni = 0; ni < 4; ni++)
        acc[mi][ni] =
            __builtin_amdgcn_mfma_f32_16x16x32_bf16(af[mi], bfr[ni], acc[mi][ni], 0, 0, 0);
  }

#pragma unroll
  for (int ni = 0; ni < 4; ni++) {
    int col = bn + wn + ni * 16 + l16;
    float bv = bias[col];
    int which = col >> 10, cc = col & 1023;  // wave-uniform per ni-tile
    int h = cc >> 6, d = cc & 63;
    if (which == 2) {
#pragma unroll
      for (int mi = 0; mi < 4; mi++) {
        int rowb = bm + wm + mi * 16 + quad * 4;
        int b = rowb >> 11, n0 = rowb & 2047;
        // key-permuted V store: swap bits 2<->3 of n within each 16-key group,
        // so k_flash's PV fragment {q-half, lane-half h} becomes one contiguous
        // 16B LDS block (read with ds_read_b128, K-like pattern).
        int n0p = (n0 & ~12) | ((n0 & 4) << 1) | ((n0 & 8) >> 1);
        bf16x4 vv;
#pragma unroll
        for (int r = 0; r < 4; r++) vv[r] = (bf16)(acc[mi][ni][r] + bv);
        *(bf16x4*)(vb + ((size_t)(b * 16 + h) * 64 + d) * 2048 + n0p) = vv;
      }
    } else {
#pragma unroll
      for (int mi = 0; mi < 4; mi++)
#pragma unroll
        for (int r = 0; r < 4; r++) {
          int row = bm + wm + mi * 16 + quad * 4 + r;
          int b = row >> 11, n = row & 2047;
          float v = acc[mi][ni][r] + bv;
          if (which == 0)
            qb[((size_t)(b * 16 + h) * 2048 + n) * 64 + d] = (bf16)(v * QSCALE);
          else
            kb[((size_t)(b * 16 + h) * 2048 + n) * 64 + d] = (bf16)v;
        }
    }
  }
}

// ---------------- output GEMM: out = A[4096,1024] @ Bt[1024,1024]^T + bias ----------
// (round-4 measured version.) 64x128 tiles, grid 512 = 2 blocks/CU, XCD-chunked.
__global__ __launch_bounds__(256, 2) void k_gemm_out(
    const bf16* __restrict__ A, const bf16* __restrict__ Bt,
    const float* __restrict__ bias, float* __restrict__ outF) {
  __shared__ __align__(16) bf16 As[64 * 32];
  __shared__ __align__(16) bf16 Bs[128 * 32];
  const int tid = threadIdx.x;
  const int lane = tid & 63, w = tid >> 6;
  const int quad = lane >> 4, l16 = lane & 15;
  const int wm = (w >> 1) * 32, wn = (w & 1) * 64;
  const int cid = (blockIdx.x & 7) * 64 + (blockIdx.x >> 3);
  const int bn = (cid & 7) * 128, bm = (cid >> 3) * 64;
  f32x4 acc[2][4] = {};

  for (int kt = 0; kt < 1024; kt += 32) {
    __syncthreads();
    {
      int idx = tid;  // As: 64 rows x 32
      int row = idx >> 2, bq = idx & 3;
      int gb = (bq - ((row >> 1) & 3)) & 3;
      GLD16(A + (size_t)(bm + row) * 1024 + kt + gb * 8, As + idx * 8);
    }
#pragma unroll
    for (int p = 0; p < 2; p++) {
      int idx = p * 256 + tid;  // Bs: 128 rows x 32
      int row = idx >> 2, bq = idx & 3;
      int gb = (bq - ((row >> 1) & 3)) & 3;
      GLD16(Bt + (size_t)(bn + row) * 1024 + kt + gb * 8, Bs + idx * 8);
    }
    __syncthreads();

    bf16x8 af[2], bfr[4];
#pragma unroll
    for (int mi = 0; mi < 2; mi++) {
      int row = wm + mi * 16 + l16;
      int bq = (quad + ((row >> 1) & 3)) & 3;
      af[mi] = *(const bf16x8*)(As + row * 32 + bq * 8);
    }
#pragma unroll
    for (int ni = 0; ni < 4; ni++) {
      int row = wn + ni * 16 + l16;
      int bq = (quad + ((row >> 1) & 3)) & 3;
      bfr[ni] = *(const bf16x8*)(Bs + row * 32 + bq * 8);
    }
#pragma unroll
    for (int mi = 0; mi < 2; mi++)
#pragma unroll
      for (int ni = 0; ni < 4; ni++)
        acc[mi][ni] =
            __builtin_amdgcn_mfma_f32_16x16x32_bf16(af[mi], bfr[ni], acc[mi][ni], 0, 0, 0);
  }

#pragma unroll
  for (int ni = 0; ni < 4; ni++) {
    int col = bn + wn + ni * 16 + l16;
    float bv = bias[col];
#pragma unroll
    for (int mi = 0; mi < 2; mi++)
#pragma unroll
      for (int r = 0; r < 4; r++) {
        int row = bm + wm + mi * 16 + quad * 4 + r;
        outF[(size_t)row * 1024 + col] = acc[mi][ni][r] + bv;
      }
  }
}

// ---------------- flash attention (32x32 MFMA, key-split waves, 16 waves/CU) ---------
// NEW decomposition: 64-row Q-tiles, 4 waves as (wq = q-half) x (wk = key-half of each
// 64-key tile), grid 1024 = 4 blocks/CU = 16 waves/CU (4 waves/SIMD, each from a
// DIFFERENT block). Every prior variant ran 2 waves/SIMD with no pipe >50% busy --
// latency-bound; this doubles TLP at the cost of 2x staging per unit compute (+20%
// LDS traffic, ~60% pipe). Per wave per iter: 4 S-MFMA + 4 PV + 2 lsum over its
// 32-key half; wk-pair partials (disjoint key sets, same q-rows/d-slots) are summed
// once at the end through LDS scratch (dead Kt/Vt space).
// P trick (per wave): S^T=K*Q^T leaves lane with key=32*wk+(reg&3)+8*(reg>>2)+4h,
// qrow=l&31; PV k-order arbitrary -> pf = exp2 of own acc regs in order; V stored
// key-permuted (bits 2<->3, in k_gemm_qkv) so each pf's V A-fragment is one b128 at
// block 4*wk+2*q+h (XOR (row&7) swizzled).
__global__ __launch_bounds__(256, 4) void k_flash(
    const bf16* __restrict__ Q, const bf16* __restrict__ K,
    const bf16* __restrict__ V, bf16* __restrict__ O) {
  __shared__ __align__(16) bf16 Kt[2][64 * 64];  // [key][d], XOR (row&7)
  __shared__ __align__(16) bf16 Vt[2][64 * 64];  // [d][key'], XOR (row&7)
  const int tid = threadIdx.x;
  const int lane = tid & 63, w = tid >> 6;
  const int wq = w >> 1, wk = w & 1;
  const int l31 = lane & 31, h = lane >> 5;
  const int x7 = l31 & 7;
  // bijective XCD chunking: 1024 = 8 x 128; qt sweeps fastest -> 4 whole heads/XCD L2
  const int cid = ((blockIdx.x & 7) << 7) | (blockIdx.x >> 3);
  const int qt = cid & 31, bh = cid >> 5;
  const bf16* qh = Q + (size_t)bh * 2048 * 64;
  const bf16* kh = K + (size_t)bh * 2048 * 64;
  const bf16* vh = V + (size_t)bh * 64 * 2048;
  const int qrow = qt * 64 + wq * 32 + l31;

  // Q fragments (B-operand of S^T = K*Q^T): slot(h,j) -> d = 16c + 8h + j
  bf16x8 qf[4];
#pragma unroll
  for (int c4 = 0; c4 < 4; c4++)
    qf[c4] = *(const bf16x8*)(qh + (size_t)qrow * 64 + c4 * 16 + h * 8);

  bf16x8 ones;
#pragma unroll
  for (int j = 0; j < 8; j++) ones[j] = (bf16)1.0f;
  f32x16 z16 = {};  // loop-invariant zero C-operand for the first S-MFMA

  f32x16 o0 = {}, o1 = {};  // partial O^T over this wave's keys
  f32x16 lacc = {};         // partial row-sum (ones-MFMA)

  auto stage = [&](int kt2, int buf) {
#pragma unroll
    for (int pp = 0; pp < 2; pp++) {
      int idx = pp * 256 + tid;
      int row = idx >> 3, bq = idx & 7, gb = bq ^ (row & 7);
      GLD16(kh + (size_t)(kt2 * 64 + row) * 64 + gb * 8, &Kt[buf][idx * 8]);
      GLD16(vh + (size_t)row * 2048 + kt2 * 64 + gb * 8, &Vt[buf][idx * 8]);
    }
  };

  stage(0, 0);

  for (int t = 0; t < 32; t++) {
    const int p = t & 1;
    __syncthreads();               // publishes buf[p]; prior readers of buf[p^1] done
    if (t < 31) stage(t + 1, p ^ 1);

    // S^T = K*Q^T over this wave's 32-key half
    f32x16 a;
    {
      const bf16* k0 = &Kt[p][0] + (wk * 32 + l31) * 64;
      __builtin_amdgcn_s_setprio(1);
#pragma unroll
      for (int c4 = 0; c4 < 4; c4++) {
        int off = ((2 * c4 + h) ^ x7) << 3;
        bf16x8 kf = *(const bf16x8*)(k0 + off);
        a = __builtin_amdgcn_mfma_f32_32x32x16_bf16(kf, qf[c4], c4 ? a : z16, 0, 0, 0);
      }
      __builtin_amdgcn_s_setprio(0);
    }

    // P = exp2(a); PV + lsum over this wave's keys
    {
      bf16x8 pf0, pf1;
#pragma unroll
      for (int j = 0; j < 8; j++) {
        pf0[j] = (bf16)__builtin_amdgcn_exp2f(a[j]);
        pf1[j] = (bf16)__builtin_amdgcn_exp2f(a[8 + j]);
      }
      const bf16* v0 = &Vt[p][0] + l31 * 64;
      const bf16* v1 = v0 + 32 * 64;
      int e0 = ((4 * wk + 0 + h) ^ x7) << 3;
      int e1 = ((4 * wk + 2 + h) ^ x7) << 3;
      bf16x8 vf00 = *(const bf16x8*)(v0 + e0);
      bf16x8 vf10 = *(const bf16x8*)(v1 + e0);
      bf16x8 vf01 = *(const bf16x8*)(v0 + e1);
      bf16x8 vf11 = *(const bf16x8*)(v1 + e1);
      __builtin_amdgcn_s_setprio(1);
      lacc = __builtin_amdgcn_mfma_f32_32x32x16_bf16(ones, pf0, lacc, 0, 0, 0);
      o0 = __builtin_amdgcn_mfma_f32_32x32x16_bf16(vf00, pf0, o0, 0, 0, 0);
      o1 = __builtin_amdgcn_mfma_f32_32x32x16_bf16(vf10, pf0, o1, 0, 0, 0);
      lacc = __builtin_amdgcn_mfma_f32_32x32x16_bf16(ones, pf1, lacc, 0, 0, 0);
      o0 = __builtin_amdgcn_mfma_f32_32x32x16_bf16(vf01, pf1, o0, 0, 0, 0);
      o1 = __builtin_amdgcn_mfma_f32_32x32x16_bf16(vf11, pf1, o1, 0, 0, 0);
      __builtin_amdgcn_s_setprio(0);
    }
  }

  // ---- combine wk-pair partials via LDS scratch (Kt/Vt dead), then store ----
  __syncthreads();  // all iter-31 LDS reads done; Kt/Vt reusable
  float* sc = (float*)&Kt[0][0];
  float* so0 = sc;                 // [2][64][17] padded (conflict-free b32)
  float* so1 = sc + 2 * 64 * 17;   // [2][64][17]
  float* sl  = sc + 4 * 64 * 17;   // [2][64]
  if (wk == 1) {
    float* b0 = so0 + (wq * 64 + lane) * 17;
    float* b1 = so1 + (wq * 64 + lane) * 17;
#pragma unroll
    for (int i = 0; i < 16; i++) { b0[i] = o0[i]; b1[i] = o1[i]; }
    sl[wq * 64 + lane] = lacc[0];
  }
  __syncthreads();
  if (wk == 0) {
    float* b0 = so0 + (wq * 64 + lane) * 17;
    float* b1 = so1 + (wq * 64 + lane) * 17;
#pragma unroll
    for (int i = 0; i < 16; i++) { o0[i] += b0[i]; o1[i] += b1[i]; }
    float inv = 1.0f / (lacc[0] + sl[wq * 64 + lane]);
    const int bb = bh >> 4, hh = bh & 15;
    bf16* orow = O + ((size_t)bb * 2048 + qrow) * 1024 + hh * 64;
#pragma unroll
    for (int g = 0; g < 4; g++) {
      bf16x4 ov0, ov1;
#pragma unroll
      for (int r = 0; r < 4; r++) {
        ov0[r] = (bf16)(o0[4 * g + r] * inv);
        ov1[r] = (bf16)(o1[4 * g + r] * inv);
      }
      *(bf16x4*)(orow + 8 * g + 4 * h) = ov0;        // d = 8g + 4h + r
      *(bf16x4*)(orow + 32 + 8 * g + 4 * h) = ov1;   // d = 32 + 8g + 4h + r
    }
  }
}

// ---------------- launch ----------------

extern "C" void kernel_launch(void* const* d_in, const int* in_sizes, int n_in,
                              void* d_out, int out_size, void* d_ws, size_t ws_size,
                              hipStream_t stream) {
  (void)in_sizes; (void)n_in; (void)out_size; (void)ws_size;
  const float* x    = (const float*)d_in[0];
  const float* Wqkv = (const float*)d_in[1];
  const float* bqkv = (const float*)d_in[2];
  const float* Wout = (const float*)d_in[3];
  const float* bout = (const float*)d_in[4];
  float* out = (float*)d_out;

  char* ws = (char*)d_ws;
  size_t off = 0;
  auto take = [&](size_t bytes) {
    char* p = ws + off;
    off += (bytes + 255) & ~(size_t)255;
    return p;
  };
  bf16* xb   = (bf16*)take((size_t)4096 * 1024 * 2);
  bf16* wqT  = (bf16*)take((size_t)3072 * 1024 * 2);
  bf16* woT  = (bf16*)take((size_t)1024 * 1024 * 2);
  bf16* qbuf = (bf16*)take((size_t)32 * 2048 * 64 * 2);
  bf16* kbuf = (bf16*)take((size_t)32 * 2048 * 64 * 2);
  bf16* vbuf = (bf16*)take((size_t)32 * 2048 * 64 * 2);
  bf16* aout = (bf16*)take((size_t)4096 * 1024 * 2);

  k_prep<<<6144, 256, 0, stream>>>(x, Wqkv, Wout, xb, wqT, woT);
  k_gemm_qkv<<<dim3(24, 32), 256, 0, stream>>>(xb, wqT, bqkv, qbuf, kbuf, vbuf);
  k_flash<<<dim3(1024), 256, 0, stream>>>(qbuf, kbuf, vbuf, aout);
  k_gemm_out<<<dim3(512), 256, 0, stream>>>(aout, woT, bout, out);
}

// Round 11
// 179.464 us; speedup vs baseline: 1.0399x; 1.0399x over previous
//
#include <hip/hip_runtime.h>
#include <hip/hip_bf16.h>
#include <cstdint>
#include <cstddef>

typedef __bf16 bf16;
typedef __bf16 bf16x4 __attribute__((ext_vector_type(4)));
typedef __bf16 bf16x8 __attribute__((ext_vector_type(8)));
typedef float f32x4 __attribute__((ext_vector_type(4)));
typedef float f32x16 __attribute__((ext_vector_type(16)));

#define LOG2E 1.4426950408889634f
#define QSCALE (0.03125f * LOG2E)   // C^-0.5 * log2(e), folded into Q

#define GLD16(gp, lp)                                                              \
  __builtin_amdgcn_global_load_lds((__attribute__((address_space(1))) void*)(gp),  \
                                   (__attribute__((address_space(3))) void*)(lp),  \
                                   16, 0, 0)

// ---------------- fused prep: x->bf16 + W_qkv^T + W_out^T (one launch) ----------------
__global__ void k_prep(const float* __restrict__ x, const float* __restrict__ Wqkv,
                       const float* __restrict__ Wout, bf16* __restrict__ xb,
                       bf16* __restrict__ wqT, bf16* __restrict__ woT) {
  const int blk = blockIdx.x, tid = threadIdx.x;
  if (blk < 2048) {  // cvt x: 2048 blocks x 256 thr x 8 elems
    int i = (blk * 256 + tid) * 8;
    const float4* p = (const float4*)(x + i);
    float4 a = p[0], b = p[1];
    bf16x8 o;
    o[0] = (bf16)a.x; o[1] = (bf16)a.y; o[2] = (bf16)a.z; o[3] = (bf16)a.w;
    o[4] = (bf16)b.x; o[5] = (bf16)b.y; o[6] = (bf16)b.z; o[7] = (bf16)b.w;
    *(bf16x8*)(xb + i) = o;
    return;
  }
  // transposes: [R][C] fp32 -> [C][R] bf16, 32x32 tiles, 256 thr as (32,8)
  const float* in;
  bf16* out;
  int R = 1024, C, bx, by;
  if (blk < 2048 + 3072) {
    in = Wqkv; out = wqT; C = 3072;
    bx = (blk - 2048) % 96; by = (blk - 2048) / 96;
  } else {
    in = Wout; out = woT; C = 1024;
    bx = (blk - 5120) % 32; by = (blk - 5120) / 32;
  }
  __shared__ float t[32][33];
  const int tx = tid & 31, ty = tid >> 5;
  int c0 = bx * 32, r0 = by * 32;
#pragma unroll
  for (int i = 0; i < 4; i++)
    t[ty + i * 8][tx] = in[(size_t)(r0 + ty + i * 8) * C + c0 + tx];
  __syncthreads();
#pragma unroll
  for (int i = 0; i < 4; i++)
    out[(size_t)(c0 + ty + i * 8) * R + r0 + tx] = (bf16)t[tx][ty + i * 8];
}

// ---------------- QKV GEMM: C = A[4096,1024] @ Bt[3072,1024]^T ----------------
// (round-4 measured version.)
__global__ __launch_bounds__(256, 3) void k_gemm_qkv(
    const bf16* __restrict__ A, const bf16* __restrict__ Bt,
    const float* __restrict__ bias,
    bf16* __restrict__ qb, bf16* __restrict__ kb, bf16* __restrict__ vb) {
  __shared__ __align__(16) bf16 As[128 * 32];
  __shared__ __align__(16) bf16 Bs[128 * 32];
  const int tid = threadIdx.x;
  const int lane = tid & 63, w = tid >> 6;
  const int quad = lane >> 4, l16 = lane & 15;
  const int wm = (w >> 1) * 64, wn = (w & 1) * 64;
  const int bm = blockIdx.y * 128, bn = blockIdx.x * 128;
  f32x4 acc[4][4] = {};

  for (int kt = 0; kt < 1024; kt += 32) {
    __syncthreads();
#pragma unroll
    for (int p = 0; p < 2; p++) {
      int idx = p * 256 + tid;
      int row = idx >> 2, bq = idx & 3;
      int gb = (bq - ((row >> 1) & 3)) & 3;
      GLD16(A + (size_t)(bm + row) * 1024 + kt + gb * 8, As + idx * 8);
      GLD16(Bt + (size_t)(bn + row) * 1024 + kt + gb * 8, Bs + idx * 8);
    }
    __syncthreads();

    bf16x8 af[4], bfr[4];
#pragma unroll
    for (int mi = 0; mi < 4; mi++) {
      int row = wm + mi * 16 + l16;
      int bq = (quad + ((row >> 1) & 3)) & 3;
      af[mi] = *(const bf16x8*)(As + row * 32 + bq * 8);
    }
#pragma unroll
    for (int ni = 0; ni < 4; ni++) {
      int row = wn + ni * 16 + l16;
      int bq = (quad + ((row >> 1) & 3)) & 3;
      bfr[ni] = *(const bf16x8*)(Bs + row * 32 + bq * 8);
    }
#pragma unroll
    for (int mi = 0; mi < 4; mi++)
#pragma unroll
      for (int ni = 0; ni < 4; ni++)
        acc[mi][ni] =
            __builtin_amdgcn_mfma_f32_16x16x32_bf16(af[mi], bfr[ni], acc[mi][ni], 0, 0, 0);
  }

#pragma unroll
  for (int ni = 0; ni < 4; ni++) {
    int col = bn + wn + ni * 16 + l16;
    float bv = bias[col];
    int which = col >> 10, cc = col & 1023;  // wave-uniform per ni-tile
    int h = cc >> 6, d = cc & 63;
    if (which == 2) {
#pragma unroll
      for (int mi = 0; mi < 4; mi++) {
        int rowb = bm + wm + mi * 16 + quad * 4;
        int b = rowb >> 11, n0 = rowb & 2047;
        // key-permuted V store: swap bits 2<->3 of n within each 16-key group,
        // so k_flash's PV fragment {q-half, lane-half h} becomes one contiguous
        // 16B LDS block (read with ds_read_b128, K-like pattern).
        int n0p = (n0 & ~12) | ((n0 & 4) << 1) | ((n0 & 8) >> 1);
        bf16x4 vv;
#pragma unroll
        for (int r = 0; r < 4; r++) vv[r] = (bf16)(acc[mi][ni][r] + bv);
        *(bf16x4*)(vb + ((size_t)(b * 16 + h) * 64 + d) * 2048 + n0p) = vv;
      }
    } else {
#pragma unroll
      for (int mi = 0; mi < 4; mi++)
#pragma unroll
        for (int r = 0; r < 4; r++) {
          int row = bm + wm + mi * 16 + quad * 4 + r;
          int b = row >> 11, n = row & 2047;
          float v = acc[mi][ni][r] + bv;
          if (which == 0)
            qb[((size_t)(b * 16 + h) * 2048 + n) * 64 + d] = (bf16)(v * QSCALE);
          else
            kb[((size_t)(b * 16 + h) * 2048 + n) * 64 + d] = (bf16)v;
        }
    }
  }
}

// ---------------- output GEMM: out = A[4096,1024] @ Bt[1024,1024]^T + bias ----------
// (round-4 measured version.) 64x128 tiles, grid 512 = 2 blocks/CU, XCD-chunked.
__global__ __launch_bounds__(256, 2) void k_gemm_out(
    const bf16* __restrict__ A, const bf16* __restrict__ Bt,
    const float* __restrict__ bias, float* __restrict__ outF) {
  __shared__ __align__(16) bf16 As[64 * 32];
  __shared__ __align__(16) bf16 Bs[128 * 32];
  const int tid = threadIdx.x;
  const int lane = tid & 63, w = tid >> 6;
  const int quad = lane >> 4, l16 = lane & 15;
  const int wm = (w >> 1) * 32, wn = (w & 1) * 64;
  const int cid = (blockIdx.x & 7) * 64 + (blockIdx.x >> 3);
  const int bn = (cid & 7) * 128, bm = (cid >> 3) * 64;
  f32x4 acc[2][4] = {};

  for (int kt = 0; kt < 1024; kt += 32) {
    __syncthreads();
    {
      int idx = tid;  // As: 64 rows x 32
      int row = idx >> 2, bq = idx & 3;
      int gb = (bq - ((row >> 1) & 3)) & 3;
      GLD16(A + (size_t)(bm + row) * 1024 + kt + gb * 8, As + idx * 8);
    }
#pragma unroll
    for (int p = 0; p < 2; p++) {
      int idx = p * 256 + tid;  // Bs: 128 rows x 32
      int row = idx >> 2, bq = idx & 3;
      int gb = (bq - ((row >> 1) & 3)) & 3;
      GLD16(Bt + (size_t)(bn + row) * 1024 + kt + gb * 8, Bs + idx * 8);
    }
    __syncthreads();

    bf16x8 af[2], bfr[4];
#pragma unroll
    for (int mi = 0; mi < 2; mi++) {
      int row = wm + mi * 16 + l16;
      int bq = (quad + ((row >> 1) & 3)) & 3;
      af[mi] = *(const bf16x8*)(As + row * 32 + bq * 8);
    }
#pragma unroll
    for (int ni = 0; ni < 4; ni++) {
      int row = wn + ni * 16 + l16;
      int bq = (quad + ((row >> 1) & 3)) & 3;
      bfr[ni] = *(const bf16x8*)(Bs + row * 32 + bq * 8);
    }
#pragma unroll
    for (int mi = 0; mi < 2; mi++)
#pragma unroll
      for (int ni = 0; ni < 4; ni++)
        acc[mi][ni] =
            __builtin_amdgcn_mfma_f32_16x16x32_bf16(af[mi], bfr[ni], acc[mi][ni], 0, 0, 0);
  }

#pragma unroll
  for (int ni = 0; ni < 4; ni++) {
    int col = bn + wn + ni * 16 + l16;
    float bv = bias[col];
#pragma unroll
    for (int mi = 0; mi < 2; mi++)
#pragma unroll
      for (int r = 0; r < 4; r++) {
        int row = bm + wm + mi * 16 + quad * 4 + r;
        outF[(size_t)row * 1024 + col] = acc[mi][ni][r] + bv;
      }
  }
}

// ---------------- flash attention (fragment-reuse: 64 q-rows x 32 keys per wave) -----
// 4-wave blocks (wq x wk), 128 q-rows/block, grid 512 = 2 blocks/CU (proven operating
// point). KEY CHANGE vs the 47.5us plateau: each wave owns TWO 32-row q-sets, so every
// K-fragment LDS read feeds 2 S-MFMAs and every V-fragment feeds 2 PV-MFMAs -- LDS
// reads (the top pipe, ~50% busy) halve per FLOP: 128KB -> 64KB per CU-iter. Waves
// split the 64-key tile (wk): per wave-iter 4 K-b128 + 4 V-b128 reads, 16 MFMA.
// Also: lsum moved OFF the matrix pipe (was 4 ones-MFMA/iter = 20% of matrix work):
// lane's S^T regs are 16 scores for ONE qrow, so row-sum = scalar VALU adds +
// shfl_xor(32) + the wk LDS combine already needed for O partials (round-0 scheme).
// P trick (per wave): S^T=K*Q^T leaves lane with key=32*wk+(reg&3)+8*(reg>>2)+4h,
// qrow(set qs)= qt*128+wq*64+qs*32+(l&31); PV k-order arbitrary -> pf = exp2 of own
// acc regs in order; V stored key-permuted (bits 2<->3, in k_gemm_qkv) so each pf's
// V A-fragment is one b128 at block 4*wk+2*ks+h (XOR (row&7) swizzled).
__global__ __launch_bounds__(256, 2) void k_flash(
    const bf16* __restrict__ Q, const bf16* __restrict__ K,
    const bf16* __restrict__ V, bf16* __restrict__ O) {
  __shared__ __align__(16) bf16 Kt[2][64 * 64];  // [key][d], XOR (row&7)
  __shared__ __align__(16) bf16 Vt[2][64 * 64];  // [d][key'], XOR (row&7)
  const int tid = threadIdx.x;
  const int lane = tid & 63, w = tid >> 6;
  const int wq = w >> 1, wk = w & 1;
  const int l31 = lane & 31, h = lane >> 5;
  const int x7 = l31 & 7;
  const int cid = ((blockIdx.x & 7) << 6) | (blockIdx.x >> 3);  // bijective XCD chunking
  const int qt = cid & 15, bh = cid >> 4;
  const bf16* qh = Q + (size_t)bh * 2048 * 64;
  const bf16* kh = K + (size_t)bh * 2048 * 64;
  const bf16* vh = V + (size_t)bh * 64 * 2048;
  const int qrow0 = qt * 128 + wq * 64 + l31;  // q-set 0; q-set 1 = qrow0 + 32

  // Q fragments, 2 q-sets (B-operand of S^T = K*Q^T): slot(h,j) -> d = 16c + 8h + j
  bf16x8 qf0[4], qf1[4];
#pragma unroll
  for (int c4 = 0; c4 < 4; c4++) {
    qf0[c4] = *(const bf16x8*)(qh + (size_t)qrow0 * 64 + c4 * 16 + h * 8);
    qf1[c4] = *(const bf16x8*)(qh + (size_t)(qrow0 + 32) * 64 + c4 * 16 + h * 8);
  }

  f32x16 z16 = {};  // loop-invariant zero C-operand for the first S-MFMA

  f32x16 oA0 = {}, oA1 = {};  // q-set 0: partial O^T, d-blocks 0/1
  f32x16 oB0 = {}, oB1 = {};  // q-set 1
  float ls0 = 0.f, ls1 = 0.f; // partial row-sums (this wave's keys, own-h half)

  auto stage = [&](int kt2, int buf) {
#pragma unroll
    for (int pp = 0; pp < 2; pp++) {
      int idx = pp * 256 + tid;
      int row = idx >> 3, bq = idx & 7, gb = bq ^ (row & 7);
      GLD16(kh + (size_t)(kt2 * 64 + row) * 64 + gb * 8, &Kt[buf][idx * 8]);
      GLD16(vh + (size_t)row * 2048 + kt2 * 64 + gb * 8, &Vt[buf][idx * 8]);
    }
  };

  stage(0, 0);

  for (int t = 0; t < 32; t++) {
    const int p = t & 1;
    __syncthreads();               // publishes buf[p]; prior readers of buf[p^1] done
    if (t < 31) stage(t + 1, p ^ 1);

    // S^T = K*Q^T over this wave's 32-key half, both q-sets share each K-fragment
    f32x16 a0, a1;
    {
      const bf16* k0 = &Kt[p][0] + (wk * 32 + l31) * 64;
      __builtin_amdgcn_s_setprio(1);
#pragma unroll
      for (int c4 = 0; c4 < 4; c4++) {
        int off = ((2 * c4 + h) ^ x7) << 3;
        bf16x8 kf = *(const bf16x8*)(k0 + off);
        a0 = __builtin_amdgcn_mfma_f32_32x32x16_bf16(kf, qf0[c4], c4 ? a0 : z16, 0, 0, 0);
        a1 = __builtin_amdgcn_mfma_f32_32x32x16_bf16(kf, qf1[c4], c4 ? a1 : z16, 0, 0, 0);
      }
      __builtin_amdgcn_s_setprio(0);
    }

    // P = exp2(S^T); scalar lsum; PV with V-fragments shared across q-sets
    {
      bf16x8 pf00, pf01, pf10, pf11;  // pf[qs][ks]
#pragma unroll
      for (int j = 0; j < 8; j++) {
        pf00[j] = (bf16)__builtin_amdgcn_exp2f(a0[j]);
        pf01[j] = (bf16)__builtin_amdgcn_exp2f(a0[8 + j]);
        pf10[j] = (bf16)__builtin_amdgcn_exp2f(a1[j]);
        pf11[j] = (bf16)__builtin_amdgcn_exp2f(a1[8 + j]);
      }
      // sum bf16-rounded values so denominator matches the PV numerator
#pragma unroll
      for (int j = 0; j < 8; j++) {
        ls0 += (float)pf00[j] + (float)pf01[j];
        ls1 += (float)pf10[j] + (float)pf11[j];
      }
      const bf16* v0 = &Vt[p][0] + l31 * 64;
      const bf16* v1 = v0 + 32 * 64;
      int e0 = ((4 * wk + 0 + h) ^ x7) << 3;
      int e1 = ((4 * wk + 2 + h) ^ x7) << 3;
      bf16x8 vf00 = *(const bf16x8*)(v0 + e0);  // vf[db][ks]
      bf16x8 vf10 = *(const bf16x8*)(v1 + e0);
      bf16x8 vf01 = *(const bf16x8*)(v0 + e1);
      bf16x8 vf11 = *(const bf16x8*)(v1 + e1);
      __builtin_amdgcn_s_setprio(1);
      oA0 = __builtin_amdgcn_mfma_f32_32x32x16_bf16(vf00, pf00, oA0, 0, 0, 0);
      oA1 = __builtin_amdgcn_mfma_f32_32x32x16_bf16(vf10, pf00, oA1, 0, 0, 0);
      oB0 = __builtin_amdgcn_mfma_f32_32x32x16_bf16(vf00, pf10, oB0, 0, 0, 0);
      oB1 = __builtin_amdgcn_mfma_f32_32x32x16_bf16(vf10, pf10, oB1, 0, 0, 0);
      oA0 = __builtin_amdgcn_mfma_f32_32x32x16_bf16(vf01, pf01, oA0, 0, 0, 0);
      oA1 = __builtin_amdgcn_mfma_f32_32x32x16_bf16(vf11, pf01, oA1, 0, 0, 0);
      oB0 = __builtin_amdgcn_mfma_f32_32x32x16_bf16(vf01, pf11, oB0, 0, 0, 0);
      oB1 = __builtin_amdgcn_mfma_f32_32x32x16_bf16(vf11, pf11, oB1, 0, 0, 0);
      __builtin_amdgcn_s_setprio(0);
    }
  }

  // cross-half (h) key-sum combine: lanes l, l^32 share a qrow, disjoint keys
  ls0 += __shfl_xor(ls0, 32, 64);
  ls1 += __shfl_xor(ls1, 32, 64);

  // ---- combine wk-pair partials via LDS scratch (Kt/Vt dead), 2 rounds (q-sets) ----
  __syncthreads();  // all iter-31 LDS reads done; Kt/Vt reusable
  float* sc = (float*)&Kt[0][0];
  float* so = sc;                  // [2 wq][64 lane][33] floats (stride-33: no conflicts)
  float* sl = sc + 2 * 64 * 33;    // [2 wq][64 lane]
  const int bb = bh >> 4, hh = bh & 15;
#pragma unroll
  for (int qs = 0; qs < 2; qs++) {
    f32x16& po0 = qs ? oB0 : oA0;
    f32x16& po1 = qs ? oB1 : oA1;
    float lsq = qs ? ls1 : ls0;
    if (wk == 1) {
      float* b = so + (wq * 64 + lane) * 33;
#pragma unroll
      for (int i = 0; i < 16; i++) { b[i] = po0[i]; b[16 + i] = po1[i]; }
      sl[wq * 64 + lane] = lsq;
    }
    __syncthreads();
    if (wk == 0) {
      float* b = so + (wq * 64 + lane) * 33;
#pragma unroll
      for (int i = 0; i < 16; i++) { po0[i] += b[i]; po1[i] += b[16 + i]; }
      float inv = 1.0f / (lsq + sl[wq * 64 + lane]);
      bf16* orow = O + ((size_t)bb * 2048 + qrow0 + qs * 32) * 1024 + hh * 64;
#pragma unroll
      for (int g = 0; g < 4; g++) {
        bf16x4 ov0, ov1;
#pragma unroll
        for (int r = 0; r < 4; r++) {
          ov0[r] = (bf16)(po0[4 * g + r] * inv);
          ov1[r] = (bf16)(po1[4 * g + r] * inv);
        }
        *(bf16x4*)(orow + 8 * g + 4 * h) = ov0;        // d = 8g + 4h + r
        *(bf16x4*)(orow + 32 + 8 * g + 4 * h) = ov1;   // d = 32 + 8g + 4h + r
      }
    }
    __syncthreads();
  }
}

// ---------------- launch ----------------

extern "C" void kernel_launch(void* const* d_in, const int* in_sizes, int n_in,
                              void* d_out, int out_size, void* d_ws, size_t ws_size,
                              hipStream_t stream) {
  (void)in_sizes; (void)n_in; (void)out_size; (void)ws_size;
  const float* x    = (const float*)d_in[0];
  const float* Wqkv = (const float*)d_in[1];
  const float* bqkv = (const float*)d_in[2];
  const float* Wout = (const float*)d_in[3];
  const float* bout = (const float*)d_in[4];
  float* out = (float*)d_out;

  char* ws = (char*)d_ws;
  size_t off = 0;
  auto take = [&](size_t bytes) {
    char* p = ws + off;
    off += (bytes + 255) & ~(size_t)255;
    return p;
  };
  bf16* xb   = (bf16*)take((size_t)4096 * 1024 * 2);
  bf16* wqT  = (bf16*)take((size_t)3072 * 1024 * 2);
  bf16* woT  = (bf16*)take((size_t)1024 * 1024 * 2);
  bf16* qbuf = (bf16*)take((size_t)32 * 2048 * 64 * 2);
  bf16* kbuf = (bf16*)take((size_t)32 * 2048 * 64 * 2);
  bf16* vbuf = (bf16*)take((size_t)32 * 2048 * 64 * 2);
  bf16* aout = (bf16*)take((size_t)4096 * 1024 * 2);

  k_prep<<<6144, 256, 0, stream>>>(x, Wqkv, Wout, xb, wqT, woT);
  k_gemm_qkv<<<dim3(24, 32), 256, 0, stream>>>(xb, wqT, bqkv, qbuf, kbuf, vbuf);
  k_flash<<<dim3(512), 256, 0, stream>>>(qbuf, kbuf, vbuf, aout);
  k_gemm_out<<<dim3(512), 256, 0, stream>>>(aout, woT, bout, out);
}

// Round 12
// 175.122 us; speedup vs baseline: 1.0656x; 1.0248x over previous
//
#include <hip/hip_runtime.h>
#include <hip/hip_bf16.h>
#include <cstdint>
#include <cstddef>

typedef __bf16 bf16;
typedef __bf16 bf16x4 __attribute__((ext_vector_type(4)));
typedef __bf16 bf16x8 __attribute__((ext_vector_type(8)));
typedef float f32x4 __attribute__((ext_vector_type(4)));
typedef float f32x16 __attribute__((ext_vector_type(16)));

#define LOG2E 1.4426950408889634f
#define QSCALE (0.03125f * LOG2E)   // C^-0.5 * log2(e), folded into Q

#define GLD16(gp, lp)                                                              \
  __builtin_amdgcn_global_load_lds((__attribute__((address_space(1))) void*)(gp),  \
                                   (__attribute__((address_space(3))) void*)(lp),  \
                                   16, 0, 0)

// ---------------- fused prep: x->bf16 + W_qkv^T + W_out^T (one launch) ----------------
__global__ void k_prep(const float* __restrict__ x, const float* __restrict__ Wqkv,
                       const float* __restrict__ Wout, bf16* __restrict__ xb,
                       bf16* __restrict__ wqT, bf16* __restrict__ woT) {
  const int blk = blockIdx.x, tid = threadIdx.x;
  if (blk < 2048) {  // cvt x: 2048 blocks x 256 thr x 8 elems
    int i = (blk * 256 + tid) * 8;
    const float4* p = (const float4*)(x + i);
    float4 a = p[0], b = p[1];
    bf16x8 o;
    o[0] = (bf16)a.x; o[1] = (bf16)a.y; o[2] = (bf16)a.z; o[3] = (bf16)a.w;
    o[4] = (bf16)b.x; o[5] = (bf16)b.y; o[6] = (bf16)b.z; o[7] = (bf16)b.w;
    *(bf16x8*)(xb + i) = o;
    return;
  }
  // transposes: [R][C] fp32 -> [C][R] bf16, 32x32 tiles, 256 thr as (32,8)
  const float* in;
  bf16* out;
  int R = 1024, C, bx, by;
  if (blk < 2048 + 3072) {
    in = Wqkv; out = wqT; C = 3072;
    bx = (blk - 2048) % 96; by = (blk - 2048) / 96;
  } else {
    in = Wout; out = woT; C = 1024;
    bx = (blk - 5120) % 32; by = (blk - 5120) / 32;
  }
  __shared__ float t[32][33];
  const int tx = tid & 31, ty = tid >> 5;
  int c0 = bx * 32, r0 = by * 32;
#pragma unroll
  for (int i = 0; i < 4; i++)
    t[ty + i * 8][tx] = in[(size_t)(r0 + ty + i * 8) * C + c0 + tx];
  __syncthreads();
#pragma unroll
  for (int i = 0; i < 4; i++)
    out[(size_t)(c0 + ty + i * 8) * R + r0 + tx] = (bf16)t[tx][ty + i * 8];
}

// ---------------- QKV GEMM: C = A[4096,1024] @ Bt[3072,1024]^T ----------------
// Round-4 structure with ONE change: BK 32 -> 64 (16 iterations instead of 32 --
// half the barrier convergences; staging 8 x GLD16/thread/iter). LDS 32KB, still
// 3 blocks/CU. Block-XOR (row&7) swizzle (flash-proven) pairs staging and reads.
__global__ __launch_bounds__(256, 3) void k_gemm_qkv(
    const bf16* __restrict__ A, const bf16* __restrict__ Bt,
    const float* __restrict__ bias,
    bf16* __restrict__ qb, bf16* __restrict__ kb, bf16* __restrict__ vb) {
  __shared__ __align__(16) bf16 As[128 * 64];
  __shared__ __align__(16) bf16 Bs[128 * 64];
  const int tid = threadIdx.x;
  const int lane = tid & 63, w = tid >> 6;
  const int quad = lane >> 4, l16 = lane & 15;
  const int wm = (w >> 1) * 64, wn = (w & 1) * 64;
  const int bm = blockIdx.y * 128, bn = blockIdx.x * 128;
  f32x4 acc[4][4] = {};

  for (int kt = 0; kt < 1024; kt += 64) {
    __syncthreads();
#pragma unroll
    for (int p = 0; p < 4; p++) {
      int idx = p * 256 + tid;          // 1024 slots = 128 rows x 8 16B-blocks
      int row = idx >> 3, bq = idx & 7;
      int gb = bq ^ (row & 7);
      GLD16(A + (size_t)(bm + row) * 1024 + kt + gb * 8, As + idx * 8);
      GLD16(Bt + (size_t)(bn + row) * 1024 + kt + gb * 8, Bs + idx * 8);
    }
    __syncthreads();

#pragma unroll
    for (int kk = 0; kk < 2; kk++) {
      bf16x8 af[4], bfr[4];
#pragma unroll
      for (int mi = 0; mi < 4; mi++) {
        int row = wm + mi * 16 + l16;
        int sb = (kk * 4 + quad) ^ (row & 7);
        af[mi] = *(const bf16x8*)(As + row * 64 + sb * 8);
      }
#pragma unroll
      for (int ni = 0; ni < 4; ni++) {
        int row = wn + ni * 16 + l16;
        int sb = (kk * 4 + quad) ^ (row & 7);
        bfr[ni] = *(const bf16x8*)(Bs + row * 64 + sb * 8);
      }
#pragma unroll
      for (int mi = 0; mi < 4; mi++)
#pragma unroll
        for (int ni = 0; ni < 4; ni++)
          acc[mi][ni] =
              __builtin_amdgcn_mfma_f32_16x16x32_bf16(af[mi], bfr[ni], acc[mi][ni], 0, 0, 0);
    }
  }

#pragma unroll
  for (int ni = 0; ni < 4; ni++) {
    int col = bn + wn + ni * 16 + l16;
    float bv = bias[col];
    int which = col >> 10, cc = col & 1023;  // wave-uniform per ni-tile
    int h = cc >> 6, d = cc & 63;
    if (which == 2) {
#pragma unroll
      for (int mi = 0; mi < 4; mi++) {
        int rowb = bm + wm + mi * 16 + quad * 4;
        int b = rowb >> 11, n0 = rowb & 2047;
        // key-permuted V store: swap bits 2<->3 of n within each 16-key group,
        // so k_flash's PV fragment {block g, half h; block g+1, half h} becomes
        // one contiguous 16B LDS block (read with ds_read_b128, K-like pattern).
        int n0p = (n0 & ~12) | ((n0 & 4) << 1) | ((n0 & 8) >> 1);
        bf16x4 vv;
#pragma unroll
        for (int r = 0; r < 4; r++) vv[r] = (bf16)(acc[mi][ni][r] + bv);
        *(bf16x4*)(vb + ((size_t)(b * 16 + h) * 64 + d) * 2048 + n0p) = vv;
      }
    } else {
#pragma unroll
      for (int mi = 0; mi < 4; mi++)
#pragma unroll
        for (int r = 0; r < 4; r++) {
          int row = bm + wm + mi * 16 + quad * 4 + r;
          int b = row >> 11, n = row & 2047;
          float v = acc[mi][ni][r] + bv;
          if (which == 0)
            qb[((size_t)(b * 16 + h) * 2048 + n) * 64 + d] = (bf16)(v * QSCALE);
          else
            kb[((size_t)(b * 16 + h) * 2048 + n) * 64 + d] = (bf16)v;
        }
    }
  }
}

// ---------------- output GEMM: out = A[4096,1024] @ Bt[1024,1024]^T + bias ----------
// Round-4 structure with BK 32 -> 64 (16 iters; 6 x GLD16/thread/iter). LDS 24KB,
// 2 blocks/CU, XCD-chunked. Block-XOR (row&7) swizzle.
__global__ __launch_bounds__(256, 2) void k_gemm_out(
    const bf16* __restrict__ A, const bf16* __restrict__ Bt,
    const float* __restrict__ bias, float* __restrict__ outF) {
  __shared__ __align__(16) bf16 As[64 * 64];
  __shared__ __align__(16) bf16 Bs[128 * 64];
  const int tid = threadIdx.x;
  const int lane = tid & 63, w = tid >> 6;
  const int quad = lane >> 4, l16 = lane & 15;
  const int wm = (w >> 1) * 32, wn = (w & 1) * 64;
  const int cid = (blockIdx.x & 7) * 64 + (blockIdx.x >> 3);
  const int bn = (cid & 7) * 128, bm = (cid >> 3) * 64;
  f32x4 acc[2][4] = {};

  for (int kt = 0; kt < 1024; kt += 64) {
    __syncthreads();
#pragma unroll
    for (int p = 0; p < 2; p++) {
      int idx = p * 256 + tid;  // As: 512 slots = 64 rows x 8 blocks
      int row = idx >> 3, bq = idx & 7;
      int gb = bq ^ (row & 7);
      GLD16(A + (size_t)(bm + row) * 1024 + kt + gb * 8, As + idx * 8);
    }
#pragma unroll
    for (int p = 0; p < 4; p++) {
      int idx = p * 256 + tid;  // Bs: 1024 slots = 128 rows x 8 blocks
      int row = idx >> 3, bq = idx & 7;
      int gb = bq ^ (row & 7);
      GLD16(Bt + (size_t)(bn + row) * 1024 + kt + gb * 8, Bs + idx * 8);
    }
    __syncthreads();

#pragma unroll
    for (int kk = 0; kk < 2; kk++) {
      bf16x8 af[2], bfr[4];
#pragma unroll
      for (int mi = 0; mi < 2; mi++) {
        int row = wm + mi * 16 + l16;
        int sb = (kk * 4 + quad) ^ (row & 7);
        af[mi] = *(const bf16x8*)(As + row * 64 + sb * 8);
      }
#pragma unroll
      for (int ni = 0; ni < 4; ni++) {
        int row = wn + ni * 16 + l16;
        int sb = (kk * 4 + quad) ^ (row & 7);
        bfr[ni] = *(const bf16x8*)(Bs + row * 64 + sb * 8);
      }
#pragma unroll
      for (int mi = 0; mi < 2; mi++)
#pragma unroll
        for (int ni = 0; ni < 4; ni++)
          acc[mi][ni] =
              __builtin_amdgcn_mfma_f32_16x16x32_bf16(af[mi], bfr[ni], acc[mi][ni], 0, 0, 0);
    }
  }

#pragma unroll
  for (int ni = 0; ni < 4; ni++) {
    int col = bn + wn + ni * 16 + l16;
    float bv = bias[col];
#pragma unroll
    for (int mi = 0; mi < 2; mi++)
#pragma unroll
      for (int r = 0; r < 4; r++) {
        int row = bm + wm + mi * 16 + quad * 4 + r;
        outF[(size_t)row * 1024 + col] = acc[mi][ni][r] + bv;
      }
  }
}

// ---------------- flash attention (round-4 version, verbatim: measured 47.6us) -------
// 4-wave blocks, grid 512 = 2 blocks/CU, dbuf K/V (32KB), one __syncthreads/iter.
// 8 variants (schedules, barriers, occupancy, read-amortization) all landed 47.3-53:
// this decomposition's fixed point. P trick: S^T=K*Q^T leaves lane with
// key=(reg&3)+8*(reg>>2)+4h, qrow=l&31; PV k-order arbitrary -> pf[c] = exp2 of own
// acc regs in order (no cross-lane, no LDS round-trip); V stored key-permuted
// (bits 2<->3, in k_gemm_qkv) so each pf[c]'s V A-fragment is one b128.
__global__ __launch_bounds__(256, 2) void k_flash(
    const bf16* __restrict__ Q, const bf16* __restrict__ K,
    const bf16* __restrict__ V, bf16* __restrict__ O) {
  __shared__ __align__(16) bf16 Kt[2][64 * 64];  // [key][d]
  __shared__ __align__(16) bf16 Vt[2][64 * 64];  // [d][key'] (key-permuted)
  const int tid = threadIdx.x;
  const int lane = tid & 63, w = tid >> 6;
  const int l31 = lane & 31, h = lane >> 5;
  const int x7 = l31 & 7;
  const int cid = ((blockIdx.x & 7) << 6) | (blockIdx.x >> 3);  // bijective XCD chunking
  const int qt = cid & 15, bh = cid >> 4;
  const bf16* qh = Q + (size_t)bh * 2048 * 64;
  const bf16* kh = K + (size_t)bh * 2048 * 64;
  const bf16* vh = V + (size_t)bh * 64 * 2048;
  const int qrow = qt * 128 + w * 32 + l31;

  // Q fragments (B-operand of S^T = K*Q^T): slot(h,j) -> d = 16c + 8h + j
  bf16x8 qf[4];
#pragma unroll
  for (int c4 = 0; c4 < 4; c4++)
    qf[c4] = *(const bf16x8*)(qh + (size_t)qrow * 64 + c4 * 16 + h * 8);

  bf16x8 ones;
#pragma unroll
  for (int j = 0; j < 8; j++) ones[j] = (bf16)1.0f;
  f32x16 z16 = {};  // loop-invariant zero C-operand for the first S-MFMA

  f32x16 o0 = {}, o1 = {};  // O^T acc: d = 32*db + (reg&3)+8*(reg>>2)+4h, col = qrow
  f32x16 lacc = {};         // ones-MFMA row-sum acc (all rows equal per col)

  auto stage = [&](int kt2, int buf) {
#pragma unroll
    for (int pp = 0; pp < 2; pp++) {
      int idx = pp * 256 + tid;
      int row = idx >> 3, bq = idx & 7, gb = bq ^ (row & 7);
      GLD16(kh + (size_t)(kt2 * 64 + row) * 64 + gb * 8, &Kt[buf][idx * 8]);
      GLD16(vh + (size_t)row * 2048 + kt2 * 64 + gb * 8, &Vt[buf][idx * 8]);
    }
  };

  stage(0, 0);

  for (int kt2 = 0; kt2 < 32; kt2++) {
    const int p = kt2 & 1;
    __syncthreads();               // publishes buf[p]; prior readers of buf[p^1] done
    if (kt2 < 31) stage(kt2 + 1, p ^ 1);
    const bf16* Kb = &Kt[p][0];
    const bf16* Vb = &Vt[p][0];

    // S^T = K*Q^T, two 32-key blocks
    f32x16 a0, a1;
    {
      const bf16* k0 = Kb + l31 * 64;
      const bf16* k1 = k0 + 32 * 64;
      __builtin_amdgcn_s_setprio(1);
#pragma unroll
      for (int c4 = 0; c4 < 4; c4++) {
        int off = ((2 * c4 + h) ^ x7) << 3;
        bf16x8 kf0 = *(const bf16x8*)(k0 + off);
        bf16x8 kf1 = *(const bf16x8*)(k1 + off);
        a0 = __builtin_amdgcn_mfma_f32_32x32x16_bf16(kf0, qf[c4], c4 ? a0 : z16, 0, 0, 0);
        a1 = __builtin_amdgcn_mfma_f32_32x32x16_bf16(kf1, qf[c4], c4 ? a1 : z16, 0, 0, 0);
      }
      __builtin_amdgcn_s_setprio(0);
    }

    const bf16* v0 = Vb + l31 * 64;
    const bf16* v1 = v0 + 32 * 64;

    // half 1: P(c=0,1) from a0, then PV + lsum MFMAs
    {
      bf16x8 pf0, pf1;
#pragma unroll
      for (int j = 0; j < 8; j++) {
        pf0[j] = (bf16)__builtin_amdgcn_exp2f(a0[j]);
        pf1[j] = (bf16)__builtin_amdgcn_exp2f(a0[8 + j]);
      }
      int e0 = ((0 + h) ^ x7) << 3, e1 = ((2 + h) ^ x7) << 3;
      bf16x8 vf00 = *(const bf16x8*)(v0 + e0);
      bf16x8 vf10 = *(const bf16x8*)(v1 + e0);
      bf16x8 vf01 = *(const bf16x8*)(v0 + e1);
      bf16x8 vf11 = *(const bf16x8*)(v1 + e1);
      __builtin_amdgcn_s_setprio(1);
      lacc = __builtin_amdgcn_mfma_f32_32x32x16_bf16(ones, pf0, lacc, 0, 0, 0);
      o0 = __builtin_amdgcn_mfma_f32_32x32x16_bf16(vf00, pf0, o0, 0, 0, 0);
      o1 = __builtin_amdgcn_mfma_f32_32x32x16_bf16(vf10, pf0, o1, 0, 0, 0);
      lacc = __builtin_amdgcn_mfma_f32_32x32x16_bf16(ones, pf1, lacc, 0, 0, 0);
      o0 = __builtin_amdgcn_mfma_f32_32x32x16_bf16(vf01, pf1, o0, 0, 0, 0);
      o1 = __builtin_amdgcn_mfma_f32_32x32x16_bf16(vf11, pf1, o1, 0, 0, 0);
      __builtin_amdgcn_s_setprio(0);
    }

    // half 2: P(c=2,3) from a1, then PV + lsum MFMAs
    {
      bf16x8 pf2, pf3;
#pragma unroll
      for (int j = 0; j < 8; j++) {
        pf2[j] = (bf16)__builtin_amdgcn_exp2f(a1[j]);
        pf3[j] = (bf16)__builtin_amdgcn_exp2f(a1[8 + j]);
      }
      int e2 = ((4 + h) ^ x7) << 3, e3 = ((6 + h) ^ x7) << 3;
      bf16x8 vf02 = *(const bf16x8*)(v0 + e2);
      bf16x8 vf12 = *(const bf16x8*)(v1 + e2);
      bf16x8 vf03 = *(const bf16x8*)(v0 + e3);
      bf16x8 vf13 = *(const bf16x8*)(v1 + e3);
      __builtin_amdgcn_s_setprio(1);
      lacc = __builtin_amdgcn_mfma_f32_32x32x16_bf16(ones, pf2, lacc, 0, 0, 0);
      o0 = __builtin_amdgcn_mfma_f32_32x32x16_bf16(vf02, pf2, o0, 0, 0, 0);
      o1 = __builtin_amdgcn_mfma_f32_32x32x16_bf16(vf12, pf2, o1, 0, 0, 0);
      lacc = __builtin_amdgcn_mfma_f32_32x32x16_bf16(ones, pf3, lacc, 0, 0, 0);
      o0 = __builtin_amdgcn_mfma_f32_32x32x16_bf16(vf03, pf3, o0, 0, 0, 0);
      o1 = __builtin_amdgcn_mfma_f32_32x32x16_bf16(vf13, pf3, o1, 0, 0, 0);
      __builtin_amdgcn_s_setprio(0);
    }
  }

  // epilogue: lacc rows all hold the full key-sum for col = qrow (both halves)
  float inv = 1.0f / lacc[0];
  const int bb = bh >> 4, hh = bh & 15;
  bf16* orow = O + ((size_t)bb * 2048 + qrow) * 1024 + hh * 64;
#pragma unroll
  for (int g = 0; g < 4; g++) {
    bf16x4 ov0, ov1;
#pragma unroll
    for (int r = 0; r < 4; r++) {
      ov0[r] = (bf16)(o0[4 * g + r] * inv);
      ov1[r] = (bf16)(o1[4 * g + r] * inv);
    }
    *(bf16x4*)(orow + 8 * g + 4 * h) = ov0;        // d = 8g + 4h + r
    *(bf16x4*)(orow + 32 + 8 * g + 4 * h) = ov1;   // d = 32 + 8g + 4h + r
  }
}

// ---------------- launch ----------------

extern "C" void kernel_launch(void* const* d_in, const int* in_sizes, int n_in,
                              void* d_out, int out_size, void* d_ws, size_t ws_size,
                              hipStream_t stream) {
  (void)in_sizes; (void)n_in; (void)out_size; (void)ws_size;
  const float* x    = (const float*)d_in[0];
  const float* Wqkv = (const float*)d_in[1];
  const float* bqkv = (const float*)d_in[2];
  const float* Wout = (const float*)d_in[3];
  const float* bout = (const float*)d_in[4];
  float* out = (float*)d_out;

  char* ws = (char*)d_ws;
  size_t off = 0;
  auto take = [&](size_t bytes) {
    char* p = ws + off;
    off += (bytes + 255) & ~(size_t)255;
    return p;
  };
  bf16* xb   = (bf16*)take((size_t)4096 * 1024 * 2);
  bf16* wqT  = (bf16*)take((size_t)3072 * 1024 * 2);
  bf16* woT  = (bf16*)take((size_t)1024 * 1024 * 2);
  bf16* qbuf = (bf16*)take((size_t)32 * 2048 * 64 * 2);
  bf16* kbuf = (bf16*)take((size_t)32 * 2048 * 64 * 2);
  bf16* vbuf = (bf16*)take((size_t)32 * 2048 * 64 * 2);
  bf16* aout = (bf16*)take((size_t)4096 * 1024 * 2);

  k_prep<<<6144, 256, 0, stream>>>(x, Wqkv, Wout, xb, wqT, woT);
  k_gemm_qkv<<<dim3(24, 32), 256, 0, stream>>>(xb, wqT, bqkv, qbuf, kbuf, vbuf);
  k_flash<<<dim3(512), 256, 0, stream>>>(qbuf, kbuf, vbuf, aout);
  k_gemm_out<<<dim3(512), 256, 0, stream>>>(aout, woT, bout, out);
}